// Round 6
// baseline (725.240 us; speedup 1.0000x reference)
//
#include <hip/hip_runtime.h>
#include <math.h>

// (B, CIN, CGD, CE, G, H, W) = (4, 256, 256, 64, 4, 80, 80)
#define NB    4
#define CINC  256
#define NG    4
#define NPIX  6400
#define NROWS 132
#define EMBW  128
#define XW    260          // xspo row: 4 groups x (64 ch + norm)
#define TEPS  1e-8f
#define TP    128
#define KC    32
#define SCH   5            // sweep channels per block (13 chunks x 5 = 65)
#define TPITCH 65
#define SENT  0xFFFFu

typedef unsigned short u16;
typedef unsigned int   u32;

__device__ __forceinline__ u16 qmul16(u16 a, u16 b) {
  u32 m = (u32)a * (u32)b;
  return (u16)((m + (m >> 16) + 32768u) >> 16);
}

// ---------------------------------------------------------------------------
// prep: trivial now — u16 parent copy + u16 inverse order (doubling sweep
// needs no levels / child ranges).
// ---------------------------------------------------------------------------
__global__ __launch_bounds__(256) void prep_kernel(
    const int* __restrict__ order, const int* __restrict__ parent,
    u16* __restrict__ par16, u16* __restrict__ inv16)
{
  int idx = blockIdx.x*256 + threadIdx.x;      // b*NPIX + k
  int b = idx / NPIX;
  int k = idx - b*NPIX;
  par16[idx] = (u16)parent[idx];
  inv16[b*NPIX + order[idx]] = (u16)k;
}

// ---------------------------------------------------------------------------
// GEMM: emb[b][n][0..127] = [W_embed@f ; W_guide@g]; confA[b][g][n] = sigmoid.
// ---------------------------------------------------------------------------
__global__ __launch_bounds__(512) void gemm_kernel(
    const float* __restrict__ f, const float* __restrict__ g,
    const float* __restrict__ We, const float* __restrict__ Wc,
    const float* __restrict__ Wg, float* __restrict__ emb,
    float* __restrict__ confA)
{
  const int b  = blockIdx.y;
  const int t0 = blockIdx.x * TP;
  const int tid = threadIdx.x;
  const int i = tid >> 5;
  const int j = tid & 31;

  __shared__ float fT[KC][TP];
  __shared__ float gT[KC][TP];
  __shared__ float wT[NROWS][KC];

  float acc[9][4];
  #pragma unroll
  for (int a = 0; a < 9; ++a)
    #pragma unroll
    for (int p = 0; p < 4; ++p) acc[a][p] = 0.f;

  const float* fb = f + (size_t)b*CINC*NPIX;
  const float* gb = g + (size_t)b*CINC*NPIX;

  for (int kc = 0; kc < CINC; kc += KC) {
    {
      int idx = tid * 8;
      int kk = idx / TP, p = idx - kk*TP;
      const float4* srcf = reinterpret_cast<const float4*>(fb + (size_t)(kc+kk)*NPIX + t0 + p);
      const float4* srcg = reinterpret_cast<const float4*>(gb + (size_t)(kc+kk)*NPIX + t0 + p);
      float4 v0 = srcf[0], v1 = srcf[1];
      fT[kk][p+0]=v0.x; fT[kk][p+1]=v0.y; fT[kk][p+2]=v0.z; fT[kk][p+3]=v0.w;
      fT[kk][p+4]=v1.x; fT[kk][p+5]=v1.y; fT[kk][p+6]=v1.z; fT[kk][p+7]=v1.w;
      v0 = srcg[0]; v1 = srcg[1];
      gT[kk][p+0]=v0.x; gT[kk][p+1]=v0.y; gT[kk][p+2]=v0.z; gT[kk][p+3]=v0.w;
      gT[kk][p+4]=v1.x; gT[kk][p+5]=v1.y; gT[kk][p+6]=v1.z; gT[kk][p+7]=v1.w;
    }
    for (int s = tid; s < 528; s += 512) {
      int idx = s * 8;
      int r = idx / KC, kb = idx - r*KC;
      const float* wsrc;
      if (r < 64)       wsrc = We + r*CINC + kc + kb;
      else if (r < 128) wsrc = Wg + (r-64)*CINC + kc + kb;
      else              wsrc = Wc + (r-128)*CINC + kc + kb;
      const float4* wv = reinterpret_cast<const float4*>(wsrc);
      float4 v0 = wv[0], v1 = wv[1];
      wT[r][kb+0]=v0.x; wT[r][kb+1]=v0.y; wT[r][kb+2]=v0.z; wT[r][kb+3]=v0.w;
      wT[r][kb+4]=v1.x; wT[r][kb+5]=v1.y; wT[r][kb+6]=v1.z; wT[r][kb+7]=v1.w;
    }
    __syncthreads();

    #pragma unroll 4
    for (int kk = 0; kk < KC; ++kk) {
      float xf0 = fT[kk][j], xf1 = fT[kk][j+32], xf2 = fT[kk][j+64], xf3 = fT[kk][j+96];
      float xg0 = gT[kk][j], xg1 = gT[kk][j+32], xg2 = gT[kk][j+64], xg3 = gT[kk][j+96];
      #pragma unroll
      for (int rr = 0; rr < 4; ++rr) {
        float a = wT[i + 16*rr][kk];
        acc[rr][0] += a*xf0; acc[rr][1] += a*xf1; acc[rr][2] += a*xf2; acc[rr][3] += a*xf3;
      }
      #pragma unroll
      for (int rr = 4; rr < 8; ++rr) {
        float a = wT[i + 16*rr][kk];
        acc[rr][0] += a*xg0; acc[rr][1] += a*xg1; acc[rr][2] += a*xg2; acc[rr][3] += a*xg3;
      }
      if (i < 4) {
        float a = wT[128 + i][kk];
        acc[8][0] += a*xf0; acc[8][1] += a*xf1; acc[8][2] += a*xf2; acc[8][3] += a*xf3;
      }
    }
    __syncthreads();
  }

  float* eb = emb + (size_t)b*NPIX*EMBW;
  #pragma unroll
  for (int rr = 0; rr < 8; ++rr) {
    int r = i + 16*rr;
    #pragma unroll
    for (int p = 0; p < 4; ++p) {
      int n = t0 + j + 32*p;
      eb[(size_t)n*EMBW + r] = acc[rr][p];
    }
  }
  if (i < 4) {
    #pragma unroll
    for (int p = 0; p < 4; ++p) {
      int n = t0 + j + 32*p;
      confA[((size_t)b*NG + i)*NPIX + n] = 1.f / (1.f + expf(-acc[8][p]));
    }
  }
}

// ---------------------------------------------------------------------------
// Edge weights: wave-per-edge coalesced row reads + shuffle reduce.
// ---------------------------------------------------------------------------
__global__ __launch_bounds__(256) void wdist_kernel(
    const float* __restrict__ emb, const int* __restrict__ order,
    const int* __restrict__ parent, const float* __restrict__ beta,
    u16* __restrict__ wq)
{
  __shared__ int s_n[64], s_np[64];
  __shared__ u16 s_wt[NG][64];
  __shared__ float s_beta[NG];
  const int bid = blockIdx.x;
  const int b = bid / 100;
  const int k0 = (bid - b*100)*64;
  const int tid = threadIdx.x;
  const int wv = tid >> 6, l = tid & 63;

  if (tid < 64) {
    int k = k0 + tid;
    s_n[tid]  = order[b*NPIX + k];
    s_np[tid] = order[b*NPIX + parent[b*NPIX + k]];
  }
  if (tid < NG) s_beta[tid] = beta[tid];
  __syncthreads();

  const float* eb = emb + (size_t)b*NPIX*EMBW;
  for (int i = 0; i < 16; ++i) {
    int e = wv*16 + i;
    const float* r0 = eb + (size_t)s_n[e]*EMBW;
    const float* r1 = eb + (size_t)s_np[e]*EMBW;
    float d0 = r0[l]    - r1[l];
    float d1 = r0[l+64] - r1[l+64];
    float d = d0*d0 + d1*d1;
    d += __shfl_xor(d, 1);
    d += __shfl_xor(d, 2);
    d += __shfl_xor(d, 4);
    d += __shfl_xor(d, 8);
    if ((l & 15) == 0) {
      int gg = l >> 4;
      float bg = s_beta[gg];
      float w = expf(-(d + bg*bg));
      s_wt[gg][e] = (u16)(w*65535.f + 0.5f);
    }
  }
  __syncthreads();
  if (tid < 128) {
    int gg = tid >> 5, j = tid & 31;
    u32* dst = (u32*)(wq + ((size_t)(b*NG+gg))*NPIX + k0);
    dst[j] = ((u32*)s_wt[gg])[j];
  }
}

// ---------------------------------------------------------------------------
// xbuild: x rows in BFS order: xspo[b][k][g*65+c]. LDS-tiled, coalesced.
// ---------------------------------------------------------------------------
__global__ __launch_bounds__(256) void xbuild_kernel(
    const float* __restrict__ f, const float* __restrict__ confA,
    const u16* __restrict__ inv16, float* __restrict__ xspo)
{
  extern __shared__ float tile[];       // [XW][TPITCH]
  __shared__ float s_cf[NG][64];
  __shared__ u16 s_k[64];
  const int bid = blockIdx.x;
  const int b = bid / 100;
  const int n0 = (bid - b*100)*64;
  const int tid = threadIdx.x;
  const int wv = tid >> 6, l = tid & 63;

  s_cf[wv][l] = confA[((size_t)b*NG + wv)*NPIX + n0 + l];
  if (tid < 64) s_k[tid] = inv16[b*NPIX + n0 + tid];
  __syncthreads();

  {
    const float* fb = f + ((size_t)b*CINC)*NPIX + n0 + l;
    float cf = s_cf[wv][l];
    for (int cc = 0; cc < 64; ++cc) {
      int ch = wv*64 + cc;
      tile[(wv*65+cc)*TPITCH + l] = fb[(size_t)ch*NPIX] * cf;
    }
    tile[(wv*65+64)*TPITCH + l] = cf;
  }
  __syncthreads();

  for (int rr = 0; rr < 16; ++rr) {
    int row = wv*16 + rr;
    float* dst = xspo + ((size_t)b*NPIX + s_k[row])*XW;
    #pragma unroll
    for (int j = 0; j < 4; ++j) {
      int c = l + j*64;
      dst[c] = tile[c*TPITCH + row];
    }
    if (l < 4) { int c = 256 + l; dst[c] = tile[c*TPITCH + row]; }
  }
}

// ---------------------------------------------------------------------------
// Tree filter via pointer doubling, LDS-resident. Block = (b,g,chunk of 5ch),
// 256 threads, XCD-swizzled blockIdx so sibling chunks share an XCD's L2.
// UP  (subtree sums):  ascending barrier-phased windows, LDS f32 atomics.
// DOWN (path scan):    descending barrier-phased windows, pure gather.
// Both: single-buffer Jacobi (anc < u ordering argument), adaptive rounds.
// ---------------------------------------------------------------------------
__global__ __launch_bounds__(256, 1) void sweep_kernel(
    float* __restrict__ xspo, const u16* __restrict__ wq,
    const u16* __restrict__ par16)
{
  extern __shared__ char smem[];
  float* A   = (float*)smem;                 // 6400*5*4 = 128000 B
  u16*  P    = (u16*)(smem + 128000);        // 12800 B
  u16*  anc  = (u16*)(smem + 140800);        // 12800 B
  u32*  P32  = (u32*)P;
  u32*  a32  = (u32*)anc;

  // XCD swizzle: bid = x + 8*(row*13 + chunk), pair p = row*8+x = b*4+g
  const int x   = blockIdx.x & 7;
  const int q   = blockIdx.x >> 3;           // 0..25
  const int row = q / 13;
  const int chunk = q - row*13;
  const int p   = row*8 + x;
  const int b   = p >> 2;
  const int g   = p & 3;
  const int off = g*65 + chunk*SCH;
  const int tid = threadIdx.x;
  const float qs = 1.0f/65535.0f;

  float* base = xspo + ((size_t)b*NPIX)*XW + off;
  const u32* ws = (const u32*)(wq + (size_t)(b*NG+g)*NPIX);
  const u32* ps = (const u32*)(par16 + (size_t)b*NPIX);

  // ---- load ----
  for (int k = tid; k < NPIX; k += 256) {
    const float* src = base + (size_t)k*XW;
    float* d = A + k*SCH;
    d[0]=src[0]; d[1]=src[1]; d[2]=src[2]; d[3]=src[3]; d[4]=src[4];
  }
  for (int i = tid; i < NPIX/2; i += 256) { P32[i] = ws[i]; a32[i] = ps[i]; }
  __syncthreads();
  if (tid == 0) anc[0] = (u16)SENT;          // root sentinel for UP
  __syncthreads();

  // ---- UP: A[u] = sum over subtree with path-weight products ----
  for (int r = 0; r < 13; ++r) {
    int myact = 0;
    // ascending scatter pass
    for (int wi = 0; wi < 7; ++wi) {
      int w0 = wi << 10;
      int nn = (w0 + 1024 <= NPIX) ? 4 : 1;
      u16 aa[4]; float pw[4]; float av[4][5];
      #pragma unroll
      for (int q2 = 0; q2 < 4; ++q2) {
        if (q2 < nn) {
          int u = w0 + q2*256 + tid;
          u16 a = anc[u];
          aa[q2] = a;
          if (a != (u16)SENT) {
            pw[q2] = (float)P[u] * qs;
            const float* s = A + u*SCH;
            av[q2][0]=s[0]; av[q2][1]=s[1]; av[q2][2]=s[2]; av[q2][3]=s[3]; av[q2][4]=s[4];
          }
        }
      }
      __syncthreads();
      #pragma unroll
      for (int q2 = 0; q2 < 4; ++q2) {
        if (q2 < nn && aa[q2] != (u16)SENT) {
          myact = 1;
          float* d = A + (int)aa[q2]*SCH;
          atomicAdd(d+0, pw[q2]*av[q2][0]);
          atomicAdd(d+1, pw[q2]*av[q2][1]);
          atomicAdd(d+2, pw[q2]*av[q2][2]);
          atomicAdd(d+3, pw[q2]*av[q2][3]);
          atomicAdd(d+4, pw[q2]*av[q2][4]);
        }
      }
      __syncthreads();
    }
    // descending anc/P update pass (Jacobi: reads target lower k, not yet written)
    for (int wi = 6; wi >= 0; --wi) {
      int w0 = wi << 10;
      int nn = (w0 + 1024 <= NPIX) ? 4 : 1;
      u16 na[4], np[4]; int act[4];
      #pragma unroll
      for (int q2 = 0; q2 < 4; ++q2) {
        act[q2] = 0;
        if (q2 < nn) {
          int u = w0 + q2*256 + tid;
          u16 a1 = anc[u];
          if (a1 != (u16)SENT) {
            act[q2] = 1;
            na[q2] = anc[a1];
            np[q2] = qmul16(P[u], P[a1]);
          }
        }
      }
      __syncthreads();
      #pragma unroll
      for (int q2 = 0; q2 < 4; ++q2) {
        if (act[q2]) {
          int u = w0 + q2*256 + tid;
          anc[u] = na[q2];
          P[u] = np[q2];
        }
      }
      __syncthreads();
    }
    if (__syncthreads_count(myact) == 0) break;
  }

  // ---- reload topology, transform to beta' ----
  for (int i = tid; i < NPIX/2; i += 256) { P32[i] = ws[i]; a32[i] = ps[i]; }
  __syncthreads();
  if (tid == 0) { anc[0] = 0; P[0] = 0; }    // absorbing root
  __syncthreads();
  for (int k = tid; k < NPIX; k += 256) {
    if (k) {
      float w = (float)P[k] * qs;
      float m = 1.f - w*w;
      float* d = A + k*SCH;
      d[0]*=m; d[1]*=m; d[2]*=m; d[3]*=m; d[4]*=m;
    }
  }
  __syncthreads();

  // ---- DOWN: S[u] += P[u]*S[anc[u]] doubling (descending = Jacobi) ----
  for (int r = 0; r < 13; ++r) {
    int myact = 0;
    for (int wi = 6; wi >= 0; --wi) {
      int w0 = wi << 10;
      int nn = (w0 + 1024 <= NPIX) ? 4 : 1;
      u16 na[4], np[4]; float pw[4]; float sA[4][5]; int act[4];
      #pragma unroll
      for (int q2 = 0; q2 < 4; ++q2) {
        act[q2] = 0;
        if (q2 < nn) {
          int u = w0 + q2*256 + tid;
          u16 pu = P[u];
          if (pu) {
            act[q2] = 1;
            u16 a = anc[u];
            pw[q2] = (float)pu * qs;
            np[q2] = qmul16(pu, P[a]);
            na[q2] = anc[a];
            const float* s = A + (int)a*SCH;
            sA[q2][0]=s[0]; sA[q2][1]=s[1]; sA[q2][2]=s[2]; sA[q2][3]=s[3]; sA[q2][4]=s[4];
          }
        }
      }
      __syncthreads();
      #pragma unroll
      for (int q2 = 0; q2 < 4; ++q2) {
        if (act[q2]) {
          myact = 1;
          int u = w0 + q2*256 + tid;
          float* d = A + u*SCH;
          d[0] += pw[q2]*sA[q2][0];
          d[1] += pw[q2]*sA[q2][1];
          d[2] += pw[q2]*sA[q2][2];
          d[3] += pw[q2]*sA[q2][3];
          d[4] += pw[q2]*sA[q2][4];
          P[u] = np[q2];
          anc[u] = na[q2];
        }
      }
      __syncthreads();
    }
    if (__syncthreads_count(myact) == 0) break;
  }

  // ---- writeback in place ----
  for (int k = tid; k < NPIX; k += 256) {
    float* dst = base + (size_t)k*XW;
    const float* s = A + k*SCH;
    dst[0]=s[0]; dst[1]=s[1]; dst[2]=s[2]; dst[3]=s[3]; dst[4]=s[4];
  }
}

// ---------------------------------------------------------------------------
// Epilogue: LDS-tiled row gather, normalize, residual, coalesced stores.
// ---------------------------------------------------------------------------
__global__ __launch_bounds__(256) void epilogue_kernel(
    const float* __restrict__ xspo, const u16* __restrict__ inv16,
    const float* __restrict__ f, const float* __restrict__ gamma,
    float* __restrict__ out)
{
  extern __shared__ float tile[];       // [XW][TPITCH]
  __shared__ u16 s_k[64];
  const int bid = blockIdx.x;
  const int b = bid / 100;
  const int n0 = (bid - b*100)*64;
  const int tid = threadIdx.x;
  const int wv = tid >> 6, l = tid & 63;

  if (tid < 64) s_k[tid] = inv16[b*NPIX + n0 + tid];
  __syncthreads();

  for (int rr = 0; rr < 16; ++rr) {
    int row = wv*16 + rr;
    const float* src = xspo + ((size_t)b*NPIX + s_k[row])*XW;
    #pragma unroll
    for (int j = 0; j < 4; ++j) {
      int c = l + j*64;
      tile[c*TPITCH + row] = src[c];
    }
    if (l < 4) { int c = 256 + l; tile[c*TPITCH + row] = src[c]; }
  }
  __syncthreads();

  float gam = gamma[0];
  float rn = 1.f / (TEPS + tile[(wv*65+64)*TPITCH + l]);
  const float* fb = f   + ((size_t)b*CINC)*NPIX + n0 + l;
  float* ob       = out + ((size_t)b*CINC)*NPIX + n0 + l;
  for (int cc = 0; cc < 64; ++cc) {
    int ch = wv*64 + cc;
    float res = tile[(wv*65+cc)*TPITCH + l] * rn;
    ob[(size_t)ch*NPIX] = fmaf(gam, res, fb[(size_t)ch*NPIX]);
  }
}

// ---------------------------------------------------------------------------
extern "C" void kernel_launch(void* const* d_in, const int* in_sizes, int n_in,
                              void* d_out, int out_size, void* d_ws, size_t ws_size,
                              hipStream_t stream)
{
  const float* f     = (const float*)d_in[0];
  const float* g     = (const float*)d_in[1];
  const float* We    = (const float*)d_in[2];
  const float* Wc    = (const float*)d_in[3];
  const float* Wg    = (const float*)d_in[4];
  const float* beta  = (const float*)d_in[5];
  const float* gamma = (const float*)d_in[6];
  const int* order   = (const int*)d_in[7];
  const int* parent  = (const int*)d_in[8];
  float* out = (float*)d_out;

  char* ws = (char*)d_ws;
  size_t off = 0;
  auto carve = [&](size_t bytes) -> void* {
    void* p = ws + off;
    off = (off + bytes + 255) & ~(size_t)255;
    return p;
  };
  float* emb   = (float*)carve((size_t)NB*NPIX*EMBW*4);
  float* confA = (float*)carve((size_t)NB*NG*NPIX*4);
  float* xspo  = (float*)carve((size_t)NB*NPIX*XW*4);
  u16* wq    = (u16*)carve((size_t)NB*NG*NPIX*2);
  u16* par16 = (u16*)carve((size_t)NB*NPIX*2);
  u16* inv16 = (u16*)carve((size_t)NB*NPIX*2);

  const int sweep_lds = 128000 + 12800 + 12800;   // 153600
  const int tile_lds  = XW*TPITCH*4;              // 67600
  hipFuncSetAttribute((const void*)sweep_kernel,
                      hipFuncAttributeMaxDynamicSharedMemorySize, sweep_lds);
  hipFuncSetAttribute((const void*)xbuild_kernel,
                      hipFuncAttributeMaxDynamicSharedMemorySize, tile_lds);
  hipFuncSetAttribute((const void*)epilogue_kernel,
                      hipFuncAttributeMaxDynamicSharedMemorySize, tile_lds);

  hipLaunchKernelGGL(prep_kernel,     dim3(NB*NPIX/256), dim3(256), 0, stream,
                     order, parent, par16, inv16);
  hipLaunchKernelGGL(gemm_kernel,     dim3(NPIX/TP, NB), dim3(512), 0, stream,
                     f, g, We, Wc, Wg, emb, confA);
  hipLaunchKernelGGL(wdist_kernel,    dim3(NB*100),      dim3(256), 0, stream,
                     emb, order, parent, beta, wq);
  hipLaunchKernelGGL(xbuild_kernel,   dim3(NB*100),      dim3(256), tile_lds, stream,
                     f, confA, inv16, xspo);
  hipLaunchKernelGGL(sweep_kernel,    dim3(NB*NG*13),    dim3(256), sweep_lds, stream,
                     xspo, wq, par16);
  hipLaunchKernelGGL(epilogue_kernel, dim3(NB*100),      dim3(256), tile_lds, stream,
                     xspo, inv16, f, gamma, out);
}

// Round 7
// 628.453 us; speedup vs baseline: 1.1540x; 1.1540x over previous
//
#include <hip/hip_runtime.h>
#include <math.h>

// (B, CIN, CGD, CE, G, H, W) = (4, 256, 256, 64, 4, 80, 80)
#define NB    4
#define CINC  256
#define NG    4
#define NPIX  6400
#define NROWS 132
#define EMBW  128
#define XW    260          // xspo row: 4 groups x (64 ch + norm)
#define TEPS  1e-8f
#define TP    128
#define KC    32
#define SCH   5            // sweep channels per block (13 chunks x 5 = 65)
#define TPITCH 65
#define LSCAP 4096         // cached level-starts (u16); global fallback past cap

typedef unsigned short u16;
typedef unsigned int   u32;

// ---------------------------------------------------------------------------
// prep: levels (pointer doubling), level starts, u16 parent, u16 child-range
// starts (parent[] monotone => contiguous children), u16 inverse order.
// ---------------------------------------------------------------------------
__global__ __launch_bounds__(256) void prep_kernel(
    const int* __restrict__ order, const int* __restrict__ parent,
    u16* __restrict__ par16, u16* __restrict__ cst16, int* __restrict__ ls,
    int* __restrict__ nl, u16* __restrict__ inv16)
{
  const int b = blockIdx.x;
  const int tid = threadIdx.x;
  const int* par = parent + b*NPIX;
  const int* ord = order + b*NPIX;
  __shared__ int lvl[NPIX];
  __shared__ int anc[NPIX];
  __shared__ int smax;

  #pragma unroll
  for (int it = 0; it < NPIX/256; ++it) {
    int k = tid + it*256;
    int p = par[k];
    lvl[k] = (k == 0) ? 0 : 1;
    anc[k] = p;
    inv16[b*NPIX + ord[k]] = (u16)k;
    par16[b*NPIX + k] = (u16)p;
  }
  __syncthreads();

  for (int r = 0; r < 13; ++r) {          // 2^13 = 8192 > 6400
    int nlv[NPIX/256], nan_[NPIX/256];
    #pragma unroll
    for (int it = 0; it < NPIX/256; ++it) {
      int k = tid + it*256;
      int a = anc[k];
      nlv[it]  = lvl[k] + lvl[a];
      nan_[it] = anc[a];
    }
    __syncthreads();
    #pragma unroll
    for (int it = 0; it < NPIX/256; ++it) {
      int k = tid + it*256;
      lvl[k] = nlv[it];
      anc[k] = nan_[it];
    }
    __syncthreads();
  }

  if (tid == 0) smax = 0;
  __syncthreads();
  int m = 0;
  #pragma unroll
  for (int it = 0; it < NPIX/256; ++it) m = max(m, lvl[tid + it*256]);
  atomicMax(&smax, m);
  __syncthreads();
  if (tid == 0) {
    nl[b] = smax + 1;
    ls[b*(NPIX+2) + smax + 1] = NPIX;
  }
  #pragma unroll
  for (int it = 0; it < NPIX/256; ++it) {
    int k = tid + it*256;
    if (k == 0 || lvl[k] != lvl[k-1]) ls[b*(NPIX+2) + lvl[k]] = k;
  }

  // reuse anc[] as LDS copy of par for binary search
  __syncthreads();
  #pragma unroll
  for (int it = 0; it < NPIX/256; ++it) { int k = tid + it*256; anc[k] = par[k]; }
  __syncthreads();
  for (int u = tid; u <= NPIX; u += 256) {
    int lo = 1, hi = NPIX;
    while (lo < hi) { int mid = (lo+hi) >> 1; if (anc[mid] < u) lo = mid+1; else hi = mid; }
    cst16[b*6402 + u] = (u16)lo;
  }
}

// ---------------------------------------------------------------------------
// GEMM: emb[b][n][0..127] = [W_embed@f ; W_guide@g]; confA[b][g][n] = sigmoid.
// ---------------------------------------------------------------------------
__global__ __launch_bounds__(512) void gemm_kernel(
    const float* __restrict__ f, const float* __restrict__ g,
    const float* __restrict__ We, const float* __restrict__ Wc,
    const float* __restrict__ Wg, float* __restrict__ emb,
    float* __restrict__ confA)
{
  const int b  = blockIdx.y;
  const int t0 = blockIdx.x * TP;
  const int tid = threadIdx.x;
  const int i = tid >> 5;
  const int j = tid & 31;

  __shared__ float fT[KC][TP];
  __shared__ float gT[KC][TP];
  __shared__ float wT[NROWS][KC];

  float acc[9][4];
  #pragma unroll
  for (int a = 0; a < 9; ++a)
    #pragma unroll
    for (int p = 0; p < 4; ++p) acc[a][p] = 0.f;

  const float* fb = f + (size_t)b*CINC*NPIX;
  const float* gb = g + (size_t)b*CINC*NPIX;

  for (int kc = 0; kc < CINC; kc += KC) {
    {
      int idx = tid * 8;
      int kk = idx / TP, p = idx - kk*TP;
      const float4* srcf = reinterpret_cast<const float4*>(fb + (size_t)(kc+kk)*NPIX + t0 + p);
      const float4* srcg = reinterpret_cast<const float4*>(gb + (size_t)(kc+kk)*NPIX + t0 + p);
      float4 v0 = srcf[0], v1 = srcf[1];
      fT[kk][p+0]=v0.x; fT[kk][p+1]=v0.y; fT[kk][p+2]=v0.z; fT[kk][p+3]=v0.w;
      fT[kk][p+4]=v1.x; fT[kk][p+5]=v1.y; fT[kk][p+6]=v1.z; fT[kk][p+7]=v1.w;
      v0 = srcg[0]; v1 = srcg[1];
      gT[kk][p+0]=v0.x; gT[kk][p+1]=v0.y; gT[kk][p+2]=v0.z; gT[kk][p+3]=v0.w;
      gT[kk][p+4]=v1.x; gT[kk][p+5]=v1.y; gT[kk][p+6]=v1.z; gT[kk][p+7]=v1.w;
    }
    for (int s = tid; s < 528; s += 512) {
      int idx = s * 8;
      int r = idx / KC, kb = idx - r*KC;
      const float* wsrc;
      if (r < 64)       wsrc = We + r*CINC + kc + kb;
      else if (r < 128) wsrc = Wg + (r-64)*CINC + kc + kb;
      else              wsrc = Wc + (r-128)*CINC + kc + kb;
      const float4* wv = reinterpret_cast<const float4*>(wsrc);
      float4 v0 = wv[0], v1 = wv[1];
      wT[r][kb+0]=v0.x; wT[r][kb+1]=v0.y; wT[r][kb+2]=v0.z; wT[r][kb+3]=v0.w;
      wT[r][kb+4]=v1.x; wT[r][kb+5]=v1.y; wT[r][kb+6]=v1.z; wT[r][kb+7]=v1.w;
    }
    __syncthreads();

    #pragma unroll 4
    for (int kk = 0; kk < KC; ++kk) {
      float xf0 = fT[kk][j], xf1 = fT[kk][j+32], xf2 = fT[kk][j+64], xf3 = fT[kk][j+96];
      float xg0 = gT[kk][j], xg1 = gT[kk][j+32], xg2 = gT[kk][j+64], xg3 = gT[kk][j+96];
      #pragma unroll
      for (int rr = 0; rr < 4; ++rr) {
        float a = wT[i + 16*rr][kk];
        acc[rr][0] += a*xf0; acc[rr][1] += a*xf1; acc[rr][2] += a*xf2; acc[rr][3] += a*xf3;
      }
      #pragma unroll
      for (int rr = 4; rr < 8; ++rr) {
        float a = wT[i + 16*rr][kk];
        acc[rr][0] += a*xg0; acc[rr][1] += a*xg1; acc[rr][2] += a*xg2; acc[rr][3] += a*xg3;
      }
      if (i < 4) {
        float a = wT[128 + i][kk];
        acc[8][0] += a*xf0; acc[8][1] += a*xf1; acc[8][2] += a*xf2; acc[8][3] += a*xf3;
      }
    }
    __syncthreads();
  }

  float* eb = emb + (size_t)b*NPIX*EMBW;
  #pragma unroll
  for (int rr = 0; rr < 8; ++rr) {
    int r = i + 16*rr;
    #pragma unroll
    for (int p = 0; p < 4; ++p) {
      int n = t0 + j + 32*p;
      eb[(size_t)n*EMBW + r] = acc[rr][p];
    }
  }
  if (i < 4) {
    #pragma unroll
    for (int p = 0; p < 4; ++p) {
      int n = t0 + j + 32*p;
      confA[((size_t)b*NG + i)*NPIX + n] = 1.f / (1.f + expf(-acc[8][p]));
    }
  }
}

// ---------------------------------------------------------------------------
// Edge weights: wave-per-edge coalesced row reads + shuffle reduce.
// ---------------------------------------------------------------------------
__global__ __launch_bounds__(256) void wdist_kernel(
    const float* __restrict__ emb, const int* __restrict__ order,
    const int* __restrict__ parent, const float* __restrict__ beta,
    u16* __restrict__ wq)
{
  __shared__ int s_n[64], s_np[64];
  __shared__ u16 s_wt[NG][64];
  __shared__ float s_beta[NG];
  const int bid = blockIdx.x;
  const int b = bid / 100;
  const int k0 = (bid - b*100)*64;
  const int tid = threadIdx.x;
  const int wv = tid >> 6, l = tid & 63;

  if (tid < 64) {
    int k = k0 + tid;
    s_n[tid]  = order[b*NPIX + k];
    s_np[tid] = order[b*NPIX + parent[b*NPIX + k]];
  }
  if (tid < NG) s_beta[tid] = beta[tid];
  __syncthreads();

  const float* eb = emb + (size_t)b*NPIX*EMBW;
  for (int i = 0; i < 16; ++i) {
    int e = wv*16 + i;
    const float* r0 = eb + (size_t)s_n[e]*EMBW;
    const float* r1 = eb + (size_t)s_np[e]*EMBW;
    float d0 = r0[l]    - r1[l];
    float d1 = r0[l+64] - r1[l+64];
    float d = d0*d0 + d1*d1;
    d += __shfl_xor(d, 1);
    d += __shfl_xor(d, 2);
    d += __shfl_xor(d, 4);
    d += __shfl_xor(d, 8);
    if ((l & 15) == 0) {
      int gg = l >> 4;
      float bg = s_beta[gg];
      float w = expf(-(d + bg*bg));
      s_wt[gg][e] = (u16)(w*65535.f + 0.5f);
    }
  }
  __syncthreads();
  if (tid < 128) {
    int gg = tid >> 5, j = tid & 31;
    u32* dst = (u32*)(wq + ((size_t)(b*NG+gg))*NPIX + k0);
    dst[j] = ((u32*)s_wt[gg])[j];
  }
}

// ---------------------------------------------------------------------------
// xbuild: x rows in BFS order: xspo[b][k][g*65+c]. LDS-tiled, coalesced.
// ---------------------------------------------------------------------------
__global__ __launch_bounds__(256) void xbuild_kernel(
    const float* __restrict__ f, const float* __restrict__ confA,
    const u16* __restrict__ inv16, float* __restrict__ xspo)
{
  extern __shared__ float tile[];       // [XW][TPITCH]
  __shared__ float s_cf[NG][64];
  __shared__ u16 s_k[64];
  const int bid = blockIdx.x;
  const int b = bid / 100;
  const int n0 = (bid - b*100)*64;
  const int tid = threadIdx.x;
  const int wv = tid >> 6, l = tid & 63;

  s_cf[wv][l] = confA[((size_t)b*NG + wv)*NPIX + n0 + l];
  if (tid < 64) s_k[tid] = inv16[b*NPIX + n0 + tid];
  __syncthreads();

  {
    const float* fb = f + ((size_t)b*CINC)*NPIX + n0 + l;
    float cf = s_cf[wv][l];
    for (int cc = 0; cc < 64; ++cc) {
      int ch = wv*64 + cc;
      tile[(wv*65+cc)*TPITCH + l] = fb[(size_t)ch*NPIX] * cf;
    }
    tile[(wv*65+64)*TPITCH + l] = cf;
  }
  __syncthreads();

  for (int rr = 0; rr < 16; ++rr) {
    int row = wv*16 + rr;
    float* dst = xspo + ((size_t)b*NPIX + s_k[row])*XW;
    #pragma unroll
    for (int j = 0; j < 4; ++j) {
      int c = l + j*64;
      dst[c] = tile[c*TPITCH + row];
    }
    if (l < 4) { int c = 256 + l; dst[c] = tile[c*TPITCH + row]; }
  }
}

// ---------------------------------------------------------------------------
// Tree filter: per-level, LDS-resident, single wave per block. Narrow levels
// (<=64 items) live in registers; cross-level dependency flows via __shfl
// (~reg crossbar) instead of LDS round trips; topology loads prefetched one
// level ahead. Wide levels use the conflict-free LDS strip path. In-place
// xspo I/O; XCD-swizzled blockIdx.
// ---------------------------------------------------------------------------
__global__ __launch_bounds__(64, 1) void sweep_kernel(
    float* __restrict__ xspo, const u16* __restrict__ wq,
    const u16* __restrict__ par16, const u16* __restrict__ cst16,
    const int* __restrict__ ls, const int* __restrict__ nl)
{
  extern __shared__ char smem[];
  float* A   = (float*)smem;                   // 128000 B
  u16* s_w   = (u16*)(smem + 128000);          // 12800 B
  u16* s_buf = (u16*)(smem + 140800);          // 12804 B (cstart then parent)
  u16* s_ls  = (u16*)(smem + 153604);          // 8192 B
  u32* w32 = (u32*)s_w; u32* b32 = (u32*)s_buf;

  // XCD swizzle: all 13 chunks of a (b,g) pair land on one XCD
  const int x   = blockIdx.x & 7;
  const int q   = blockIdx.x >> 3;             // 0..25
  const int row = q / 13;
  const int chunk = q - row*13;
  const int pr  = row*8 + x;
  const int b   = pr >> 2;
  const int g   = pr & 3;
  const int off = g*65 + chunk*SCH;
  const int tid = threadIdx.x;
  const float qs = 1.0f/65535.0f;

  float* base = xspo + ((size_t)b*NPIX)*XW + off;
  const u32* ws = (const u32*)(wq + (size_t)(b*NG+g)*NPIX);
  const u32* ps = (const u32*)(par16 + (size_t)b*NPIX);
  const u32* cs = (const u32*)(cst16 + (size_t)b*6402);
  const int* lsb = ls + b*(NPIX+2);
  const int L = nl[b];
  const int lcap = (L < LSCAP-1) ? L : LSCAP-1;   // cache indices 0..lcap

  // ---- load ----
  for (int k = tid; k < NPIX; k += 64) {
    const float* src = base + (size_t)k*XW;
    float* d = A + k*5;
    d[0]=src[0]; d[1]=src[1]; d[2]=src[2]; d[3]=src[3]; d[4]=src[4];
  }
  for (int i = tid; i < 3200; i += 64) w32[i] = ws[i];
  for (int i = tid; i < 3201; i += 64) b32[i] = cs[i];
  for (int i = tid; i <= lcap; i += 64) s_ls[i] = (u16)lsb[i];
  __syncthreads();

  auto getls = [&](int i) -> int {
    return (i <= lcap) ? (int)s_ls[i] : lsb[i];
  };

  // ================= UP: a[u] = x[u] + sum_children w_j * a[j] =============
  {
    int lev = L-2;
    bool preg = false;
    float wav = 0.f;
    while (lev >= 0) {
      int s = getls(lev), e = getls(lev+1);
      int nitems = (e - s)*5;
      if (nitems > 64) {
        for (int t = tid; t < nitems; t += 64) {
          int node = s + t/5, c = t - (t/5)*5;
          float sum = A[node*5+c];
          int j0 = s_buf[node], j1 = s_buf[node+1];
          for (int j = j0; j < j1; ++j)
            sum += (float)s_w[j]*qs * A[j*5+c];
          A[node*5+c] = sum;
        }
        preg = false;
        --lev;
        continue;
      }
      // narrow run with 1-level prefetch
      int d = (lev >= 1) ? getls(lev-1) : 0;
      bool act = tid < nitems;
      int tt = act ? tid : 0;
      int node = s + tt/5, c = tt - (tt/5)*5;
      float xv = A[node*5+c];
      float wn = (float)s_w[node]*qs;
      int j0 = s_buf[node], j1 = s_buf[node+1];
      for (;;) {
        int items_n = (s - d)*5;               // level lev-1
        bool narrow_n = (lev >= 1) && (items_n <= 64);
        // prefetch level lev-1 state (independent of the value chain)
        int tn = (tid < items_n) ? tid : 0;
        int node_n = d + tn/5, c_n = tn - (tn/5)*5;
        float x_n = 0.f, w_n = 0.f; int j0_n = 0, j1_n = 0;
        if (narrow_n) {
          x_n = A[node_n*5+c_n];
          w_n = (float)s_w[node_n]*qs;
          j0_n = s_buf[node_n];
          j1_n = s_buf[node_n+1];
        }
        // compute current level lev (children start at e)
        float sum = xv;
        if (preg) {
          #pragma unroll
          for (int t2 = 0; t2 < 4; ++t2) {     // grid degree <= 4
            int j = j0 + t2;
            int lj = ((j - e)*5 + c) & 63;
            float wa = __shfl(wav, lj, 64);
            sum += (j < j1) ? wa : 0.f;
          }
        } else {
          for (int j = j0; j < j1; ++j)
            sum += (float)s_w[j]*qs * A[j*5+c];
        }
        if (act) A[node*5+c] = sum;
        wav = wn * sum;
        preg = true;
        --lev;
        if (lev < 0) break;
        e = s; s = d; d = (lev >= 1) ? getls(lev-1) : 0;
        if (!narrow_n) break;
        act = tid < items_n;
        node = node_n; c = c_n; xv = x_n; wn = w_n; j0 = j0_n; j1 = j1_n;
      }
    }
  }

  // ---- reload buf with parent ----
  __syncthreads();
  for (int i = tid; i < 3200; i += 64) b32[i] = ps[i];
  __syncthreads();

  // ============ DOWN: out[k] = a + w*(out[p] - w*a), in place ==============
  {
    int lev = 1;
    bool preg = false;
    float vout = 0.f;
    while (lev < L) {
      int s = getls(lev), e = getls(lev+1);
      int nitems = (e - s)*5;
      if (nitems > 64) {
        for (int t = tid; t < nitems; t += 64) {
          int node = s + t/5, c = t - (t/5)*5;
          int p = s_buf[node];
          float wn = (float)s_w[node]*qs;
          float a  = A[node*5+c];
          float op = A[p*5+c];
          A[node*5+c] = fmaf(wn, op - wn*a, a);
        }
        preg = false;
        ++lev;
        continue;
      }
      // narrow run with 1-level prefetch
      int sprev = getls(lev-1);
      int f2 = (lev+2 <= L) ? getls(lev+2) : NPIX;
      bool act = tid < nitems;
      int tt = act ? tid : 0;
      int node = s + tt/5, c = tt - (tt/5)*5;
      float a = A[node*5+c];
      float wn = (float)s_w[node]*qs;
      int p = s_buf[node];
      for (;;) {
        int items_n = (f2 - e)*5;              // level lev+1
        bool narrow_n = (items_n <= 64);
        int tn = (tid < items_n) ? tid : 0;
        int node_n = e + tn/5, c_n = tn - (tn/5)*5;
        float a_n = 0.f, w_n = 0.f; int p_n = 0;
        if (narrow_n) {
          a_n = A[node_n*5+c_n];
          w_n = (float)s_w[node_n]*qs;
          p_n = s_buf[node_n];
        }
        // compute current level lev (parents start at sprev)
        float op;
        if (preg) {
          int lp = ((p - sprev)*5 + c) & 63;
          op = __shfl(vout, lp, 64);
        } else {
          op = A[p*5+c];
        }
        float o = fmaf(wn, op - wn*a, a);
        if (act) A[node*5+c] = o;
        vout = o;
        preg = true;
        ++lev;
        if (lev >= L) break;
        sprev = s; s = e; e = f2;
        f2 = (lev+2 <= L) ? getls(lev+2) : NPIX;
        if (!narrow_n) break;
        act = tid < items_n;
        node = node_n; c = c_n; a = a_n; wn = w_n; p = p_n;
      }
    }
  }

  // ---- writeback in place ----
  __syncthreads();
  for (int k = tid; k < NPIX; k += 64) {
    float* dst = base + (size_t)k*XW;
    const float* src = A + k*5;
    dst[0]=src[0]; dst[1]=src[1]; dst[2]=src[2]; dst[3]=src[3]; dst[4]=src[4];
  }
}

// ---------------------------------------------------------------------------
// Epilogue: LDS-tiled row gather, normalize, residual, coalesced stores.
// ---------------------------------------------------------------------------
__global__ __launch_bounds__(256) void epilogue_kernel(
    const float* __restrict__ xspo, const u16* __restrict__ inv16,
    const float* __restrict__ f, const float* __restrict__ gamma,
    float* __restrict__ out)
{
  extern __shared__ float tile[];       // [XW][TPITCH]
  __shared__ u16 s_k[64];
  const int bid = blockIdx.x;
  const int b = bid / 100;
  const int n0 = (bid - b*100)*64;
  const int tid = threadIdx.x;
  const int wv = tid >> 6, l = tid & 63;

  if (tid < 64) s_k[tid] = inv16[b*NPIX + n0 + tid];
  __syncthreads();

  for (int rr = 0; rr < 16; ++rr) {
    int row = wv*16 + rr;
    const float* src = xspo + ((size_t)b*NPIX + s_k[row])*XW;
    #pragma unroll
    for (int j = 0; j < 4; ++j) {
      int c = l + j*64;
      tile[c*TPITCH + row] = src[c];
    }
    if (l < 4) { int c = 256 + l; tile[c*TPITCH + row] = src[c]; }
  }
  __syncthreads();

  float gam = gamma[0];
  float rn = 1.f / (TEPS + tile[(wv*65+64)*TPITCH + l]);
  const float* fb = f   + ((size_t)b*CINC)*NPIX + n0 + l;
  float* ob       = out + ((size_t)b*CINC)*NPIX + n0 + l;
  for (int cc = 0; cc < 64; ++cc) {
    int ch = wv*64 + cc;
    float res = tile[(wv*65+cc)*TPITCH + l] * rn;
    ob[(size_t)ch*NPIX] = fmaf(gam, res, fb[(size_t)ch*NPIX]);
  }
}

// ---------------------------------------------------------------------------
extern "C" void kernel_launch(void* const* d_in, const int* in_sizes, int n_in,
                              void* d_out, int out_size, void* d_ws, size_t ws_size,
                              hipStream_t stream)
{
  const float* f     = (const float*)d_in[0];
  const float* g     = (const float*)d_in[1];
  const float* We    = (const float*)d_in[2];
  const float* Wc    = (const float*)d_in[3];
  const float* Wg    = (const float*)d_in[4];
  const float* beta  = (const float*)d_in[5];
  const float* gamma = (const float*)d_in[6];
  const int* order   = (const int*)d_in[7];
  const int* parent  = (const int*)d_in[8];
  float* out = (float*)d_out;

  char* ws = (char*)d_ws;
  size_t off = 0;
  auto carve = [&](size_t bytes) -> void* {
    void* p = ws + off;
    off = (off + bytes + 255) & ~(size_t)255;
    return p;
  };
  float* emb   = (float*)carve((size_t)NB*NPIX*EMBW*4);
  float* confA = (float*)carve((size_t)NB*NG*NPIX*4);
  float* xspo  = (float*)carve((size_t)NB*NPIX*XW*4);
  u16* wq    = (u16*)carve((size_t)NB*NG*NPIX*2);
  u16* par16 = (u16*)carve((size_t)NB*NPIX*2);
  u16* cst16 = (u16*)carve((size_t)NB*6402*2);
  u16* inv16 = (u16*)carve((size_t)NB*NPIX*2);
  int* ls    = (int*)carve((size_t)NB*(NPIX+2)*4);
  int* nl    = (int*)carve((size_t)NB*4);

  const int sweep_lds = 128000 + 12800 + 12804 + 2*LSCAP;   // 161796
  const int tile_lds  = XW*TPITCH*4;                        // 67600
  hipFuncSetAttribute((const void*)sweep_kernel,
                      hipFuncAttributeMaxDynamicSharedMemorySize, sweep_lds);
  hipFuncSetAttribute((const void*)xbuild_kernel,
                      hipFuncAttributeMaxDynamicSharedMemorySize, tile_lds);
  hipFuncSetAttribute((const void*)epilogue_kernel,
                      hipFuncAttributeMaxDynamicSharedMemorySize, tile_lds);

  hipLaunchKernelGGL(prep_kernel,     dim3(NB),          dim3(256), 0, stream,
                     order, parent, par16, cst16, ls, nl, inv16);
  hipLaunchKernelGGL(gemm_kernel,     dim3(NPIX/TP, NB), dim3(512), 0, stream,
                     f, g, We, Wc, Wg, emb, confA);
  hipLaunchKernelGGL(wdist_kernel,    dim3(NB*100),      dim3(256), 0, stream,
                     emb, order, parent, beta, wq);
  hipLaunchKernelGGL(xbuild_kernel,   dim3(NB*100),      dim3(256), tile_lds, stream,
                     f, confA, inv16, xspo);
  hipLaunchKernelGGL(sweep_kernel,    dim3(NB*NG*13),    dim3(64),  sweep_lds, stream,
                     xspo, wq, par16, cst16, ls, nl);
  hipLaunchKernelGGL(epilogue_kernel, dim3(NB*100),      dim3(256), tile_lds, stream,
                     xspo, inv16, f, gamma, out);
}